// Round 4
// baseline (325.152 us; speedup 1.0000x reference)
//
#include <hip/hip_runtime.h>
#include <hip/hip_bf16.h>
#include <math.h>

typedef float f32x4 __attribute__((ext_vector_type(4)));
typedef short s16x8 __attribute__((ext_vector_type(8)));
typedef unsigned short us;

typedef const __attribute__((address_space(1))) unsigned int* gas1_t;
typedef __attribute__((address_space(3))) unsigned int* las3_t;

__device__ __forceinline__ void load_lds16(const void* g, void* l) {
  __builtin_amdgcn_global_load_lds((gas1_t)g, (las3_t)l, 16, 0, 0);
}

__device__ __forceinline__ us f2bf(float f) {
  union { float f; unsigned u; } v; v.f = f;
  unsigned u = v.u;
  u += 0x7fffu + ((u >> 16) & 1u);   // RNE
  return (us)(u >> 16);
}

// ---------------- prep: LayerNorm rows (text, av) + weight f32->bf16 converts ----------------
__global__ __launch_bounds__(256) void prep_kernel(
    const float* __restrict__ text, const float* __restrict__ av,
    const float* __restrict__ tn_w, const float* __restrict__ tn_b,
    const float* __restrict__ an_w, const float* __restrict__ an_b,
    const float* __restrict__ Wq, const float* __restrict__ Wk, const float* __restrict__ Wv,
    us* __restrict__ Tln, us* __restrict__ Aln,
    us* __restrict__ Wqb, us* __restrict__ Wkb, us* __restrict__ Wvb) {
  int id = blockIdx.x, tid = threadIdx.x;
  if (id >= 12288) {
    int c = id - 12288;
    const float* src; us* dst;
    if (c < 1024)      { src = Wq; dst = Wqb; }
    else if (c < 2048) { src = Wk; dst = Wkb; c -= 1024; }
    else               { src = Wv; dst = Wvb; c -= 2048; }
    int i = c * 256 + tid;
    float4 v = ((const float4*)src)[i];
    ushort4 o;
    o.x = f2bf(v.x); o.y = f2bf(v.y); o.z = f2bf(v.z); o.w = f2bf(v.w);
    ((ushort4*)dst)[i] = o;
    return;
  }
  const float *x, *w, *b; us* outp; int row;
  if (id < 4096) { x = text; w = tn_w; b = tn_b; outp = Tln; row = id; }
  else           { x = av;   w = an_w; b = an_b; outp = Aln; row = id - 4096; }
  const float4* xr = (const float4*)(x + (size_t)row * 1024);
  float4 v = xr[tid];
  float s  = v.x + v.y + v.z + v.w;
  float ss = v.x * v.x + v.y * v.y + v.z * v.z + v.w * v.w;
  #pragma unroll
  for (int off = 32; off; off >>= 1) {
    s  += __shfl_down(s, off);
    ss += __shfl_down(ss, off);
  }
  __shared__ float red[8];
  int wid = tid >> 6, lane = tid & 63;
  if (lane == 0) { red[wid] = s; red[wid + 4] = ss; }
  __syncthreads();
  s  = red[0] + red[1] + red[2] + red[3];
  ss = red[4] + red[5] + red[6] + red[7];
  float mu  = s * (1.0f / 1024.0f);
  float var = ss * (1.0f / 1024.0f) - mu * mu;
  float rstd = rsqrtf(var + 1e-5f);
  float4 wv = ((const float4*)w)[tid];
  float4 bv = ((const float4*)b)[tid];
  ushort4 o;
  o.x = f2bf((v.x - mu) * rstd * wv.x + bv.x);
  o.y = f2bf((v.y - mu) * rstd * wv.y + bv.y);
  o.z = f2bf((v.z - mu) * rstd * wv.z + bv.z);
  o.w = f2bf((v.w - mu) * rstd * wv.w + bv.w);
  ((ushort4*)(outp + (size_t)row * 1024))[tid] = o;
}

// ---------------- fused triple NT-GEMM, dbuf LDS + XCD-stripe swizzle ----------------
// Swizzle: XCD x (= bid%8) owns a contiguous A-row stripe (2MB) + its B (2MB) -> fits 4MB L2.
__global__ __launch_bounds__(256) void gemm3_kernel(
    const us* __restrict__ Tln, const us* __restrict__ Aln,
    const us* __restrict__ Wqb, const us* __restrict__ Wkb, const us* __restrict__ Wvb,
    const float* __restrict__ bq, const float* __restrict__ bk_, const float* __restrict__ bv_,
    us* __restrict__ Qb, us* __restrict__ Kb, us* __restrict__ Vtb) {
  __shared__ us As[2][128 * 32];
  __shared__ us Bs[2][128 * 32];
  const int K = 1024, N = 1024;
  int id = blockIdx.x;
  const us *A, *B; const float* bias; us* C; bool trans = false;
  int rb, cb;
  if (id < 256) {
    A = Tln; B = Wqb; bias = bq; C = Qb;
    int x = id & 7, y = id >> 3;            // y 0..31
    rb = x * 4 + (y >> 3); cb = y & 7;      // rb 0..31
  } else if (id < 768) {
    int l = id - 256; A = Aln; B = Wkb; bias = bk_; C = Kb;
    int x = l & 7, y = l >> 3;              // y 0..63
    rb = x * 8 + (y >> 3); cb = y & 7;      // rb 0..63
  } else {
    int l = id - 768; A = Aln; B = Wvb; bias = bv_; C = Vtb; trans = true;
    int x = l & 7, y = l >> 3;
    rb = x * 8 + (y >> 3); cb = y & 7;
  }
  int row0 = rb * 128, col0 = cb * 128;
  int tid = threadIdx.x, lane = tid & 63, wid = tid >> 6;
  int wr = wid >> 1, wc = wid & 1;
  int l15 = lane & 15, kof = (lane >> 4) * 8, lg = lane >> 4;
  int ch0 = wid * 64 + lane, ch1 = ch0 + 256;
  int r0 = ch0 >> 2, c0 = ch0 & 3, r1 = ch1 >> 2, c1 = ch1 & 3;

#define G3_STAGE(buf, kt)                                                       \
  { load_lds16(&A[(size_t)(row0 + r0) * K + (kt) + c0 * 8], &As[buf][ch0 * 8]); \
    load_lds16(&B[(size_t)(col0 + r0) * K + (kt) + c0 * 8], &Bs[buf][ch0 * 8]); \
    load_lds16(&A[(size_t)(row0 + r1) * K + (kt) + c1 * 8], &As[buf][ch1 * 8]); \
    load_lds16(&B[(size_t)(col0 + r1) * K + (kt) + c1 * 8], &Bs[buf][ch1 * 8]); }

  f32x4 acc[4][4] = {};
  G3_STAGE(0, 0);
  __syncthreads();
  int cur = 0;
  for (int kt = 0; kt < K; kt += 32) {
    if (kt + 32 < K) G3_STAGE(cur ^ 1, kt + 32);
    s16x8 af[4], bfr[4];
    #pragma unroll
    for (int m = 0; m < 4; ++m)
      af[m] = *(const s16x8*)&As[cur][(wr * 64 + m * 16 + l15) * 32 + kof];
    #pragma unroll
    for (int n = 0; n < 4; ++n)
      bfr[n] = *(const s16x8*)&Bs[cur][(wc * 64 + n * 16 + l15) * 32 + kof];
    #pragma unroll
    for (int m = 0; m < 4; ++m)
      #pragma unroll
      for (int n = 0; n < 4; ++n)
        acc[m][n] = __builtin_amdgcn_mfma_f32_16x16x32_bf16(af[m], bfr[n], acc[m][n], 0, 0, 0);
    __syncthreads();
    cur ^= 1;
  }
  if (trans) {
    int b = row0 >> 10;
    int kbase = (row0 & 1023) + wr * 64 + lg * 4;
    #pragma unroll
    for (int n = 0; n < 4; ++n) {
      int col = col0 + wc * 64 + n * 16 + l15;
      float bb = bias[col];
      us* cp = C + (size_t)b * 1048576 + (size_t)col * 1024 + kbase;
      #pragma unroll
      for (int m = 0; m < 4; ++m) {
        ushort4 o;
        o.x = f2bf(acc[m][n][0] + bb);
        o.y = f2bf(acc[m][n][1] + bb);
        o.z = f2bf(acc[m][n][2] + bb);
        o.w = f2bf(acc[m][n][3] + bb);
        *(ushort4*)(cp + m * 16) = o;
      }
    }
  } else {
    #pragma unroll
    for (int n = 0; n < 4; ++n) {
      int col = col0 + wc * 64 + n * 16 + l15;
      float bb = bias[col];
      #pragma unroll
      for (int m = 0; m < 4; ++m)
        #pragma unroll
        for (int j = 0; j < 4; ++j) {
          int row = row0 + wr * 64 + m * 16 + lg * 4 + j;
          C[(size_t)row * N + col] = f2bf(acc[m][n][j] + bb);
        }
    }
  }
#undef G3_STAGE
}

// ---------------- Fused sigmoid cross-attention (swapped-QK, kperm, zero P-exchange) ----------------
// grid 256: bid -> (b=bid&7 [XCD-pinned], qt=bid>>3), QBLK=16 q-rows.
// block 512 thr = 8 waves: (g = wv>>1: heads 4g..4g+3, s = wv&1: key-half).
// Swapped S^T = mfma(Kfrag, Qfrag) with K rows loaded in kperm order so the C-layout
// equals the PV B-frag layout directly (no LDS, no lane exchange for P).
// LDS: mean partials (bf16, dbuf, 1 barrier/tile) + one-time O transpose buffer.
#define MSTR 34
__global__ __launch_bounds__(512, 2) void attn_kernel(
    const us* __restrict__ Q, const us* __restrict__ K,
    const us* __restrict__ Vt, float* __restrict__ out,
    float* __restrict__ meanout) {
  __shared__ float Obuf[16 * 513];           // 32.8 KB
  __shared__ us Mbuf[2][2][4][16 * MSTR];    // 17.4 KB  [par][s][g][q*MSTR+k]
  int bid = blockIdx.x;
  int b = bid & 7, qt = bid >> 3;
  int q0 = qt * 16;
  int tid = threadIdx.x, lane = tid & 63, wv = tid >> 6;
  int g = wv >> 1, s = wv & 1;
  int l15 = lane & 15, lg = lane >> 4;
  const float SC = -0.1803368801111244f;     // -(1/8)*log2(e)

  // Q B-frags (col=q=l15, k=d=lg*8+j), per head hh: h = g*4+hh
  s16x8 aq[4][2];
  #pragma unroll
  for (int hh = 0; hh < 4; ++hh)
    #pragma unroll
    for (int ks = 0; ks < 2; ++ks)
      aq[hh][ks] = *(const s16x8*)(Q + (size_t)(b * 512 + q0 + l15) * 1024 +
                                   (g * 4 + hh) * 64 + ks * 32 + lg * 8);

  f32x4 oacc[4][4] = {};   // [hh][nd] : O^T frags (row=d, col=q)

  int klo = 8 * (l15 >> 2) + (l15 & 3);      // kperm row->key (lo MFMA); hi = +4
  const us* Kbase = K + ((size_t)b * 1024 + s * 512) * 1024;
  const us* Vbase = Vt + (size_t)b * 1048576 + s * 512;

  for (int t = 0; t < 16; ++t) {
    int kt = t * 32;
    // K A-frags, kperm rows
    s16x8 kf[4][2][2];  // [hh][half][ks]
    #pragma unroll
    for (int hh = 0; hh < 4; ++hh)
      #pragma unroll
      for (int hf = 0; hf < 2; ++hf)
        #pragma unroll
        for (int ks = 0; ks < 2; ++ks)
          kf[hh][hf][ks] = *(const s16x8*)(Kbase + (size_t)(kt + klo + hf * 4) * 1024 +
                                           (g * 4 + hh) * 64 + ks * 32 + lg * 8);
    // S^T = K Q^T
    f32x4 slo[4], shi[4];
    #pragma unroll
    for (int hh = 0; hh < 4; ++hh) {
      f32x4 z = {};
      z = __builtin_amdgcn_mfma_f32_16x16x32_bf16(kf[hh][0][0], aq[hh][0], z, 0, 0, 0);
      slo[hh] = __builtin_amdgcn_mfma_f32_16x16x32_bf16(kf[hh][0][1], aq[hh][1], z, 0, 0, 0);
      f32x4 z2 = {};
      z2 = __builtin_amdgcn_mfma_f32_16x16x32_bf16(kf[hh][1][0], aq[hh][0], z2, 0, 0, 0);
      shi[hh] = __builtin_amdgcn_mfma_f32_16x16x32_bf16(kf[hh][1][1], aq[hh][1], z2, 0, 0, 0);
    }
    // V^T A-frags (row=d=l15, k=key=lg*8+j) — issued early to hide latency under sigmoid
    s16x8 vf[4][4];  // [hh][nd]
    #pragma unroll
    for (int hh = 0; hh < 4; ++hh)
      #pragma unroll
      for (int nd = 0; nd < 4; ++nd)
        vf[hh][nd] = *(const s16x8*)(Vbase + (size_t)((g * 4 + hh) * 64 + nd * 16 + l15) * 1024 +
                                     kt + lg * 8);
    // sigmoid -> pb (B-frag of PV, keys 8*lg+j lane-local by kperm) + mean partial
    float p4[8] = {0, 0, 0, 0, 0, 0, 0, 0};
    s16x8 pb[4];
    #pragma unroll
    for (int hh = 0; hh < 4; ++hh) {
      float pl[4], ph[4];
      #pragma unroll
      for (int j = 0; j < 4; ++j) {
        pl[j] = __builtin_amdgcn_rcpf(1.0f + exp2f(slo[hh][j] * SC));
        ph[j] = __builtin_amdgcn_rcpf(1.0f + exp2f(shi[hh][j] * SC));
        p4[j] += pl[j];
        p4[4 + j] += ph[j];
      }
      union { s16x8 v; unsigned u[4]; } pk;
      asm("v_cvt_pk_bf16_f32 %0, %1, %2" : "=v"(pk.u[0]) : "v"(pl[0]), "v"(pl[1]));
      asm("v_cvt_pk_bf16_f32 %0, %1, %2" : "=v"(pk.u[1]) : "v"(pl[2]), "v"(pl[3]));
      asm("v_cvt_pk_bf16_f32 %0, %1, %2" : "=v"(pk.u[2]) : "v"(ph[0]), "v"(ph[1]));
      asm("v_cvt_pk_bf16_f32 %0, %1, %2" : "=v"(pk.u[3]) : "v"(ph[2]), "v"(ph[3]));
      pb[hh] = pk.v;
    }
    // O^T += V^T P^T
    #pragma unroll
    for (int hh = 0; hh < 4; ++hh)
      #pragma unroll
      for (int nd = 0; nd < 4; ++nd)
        oacc[hh][nd] = __builtin_amdgcn_mfma_f32_16x16x32_bf16(vf[hh][nd], pb[hh], oacc[hh][nd], 0, 0, 0);
    // mean partials: lane (q=l15, kg=lg) holds keys 8*lg + (0..7)
    {
      us* mb = &Mbuf[t & 1][s][g][l15 * MSTR + 8 * lg];
      #pragma unroll
      for (int i = 0; i < 8; ++i) mb[i] = f2bf(p4[i]);
    }
    __syncthreads();
    // reduce over 4 head-groups, write mean
    {
      int s2 = tid >> 8, q = (tid >> 4) & 15, k2 = (tid & 15) * 2;
      float m0 = 0.f, m1 = 0.f;
      #pragma unroll
      for (int gg = 0; gg < 4; ++gg) {
        unsigned u = *(const unsigned*)&Mbuf[t & 1][s2][gg][q * MSTR + k2];
        union { unsigned u; float f; } lo, hi;
        lo.u = u << 16; hi.u = u & 0xffff0000u;
        m0 += lo.f; m1 += hi.f;
      }
      float2 mo; mo.x = m0 * 0.0625f; mo.y = m1 * 0.0625f;
      *(float2*)&meanout[(size_t)(b * 512 + q0 + q) * 1024 + s2 * 512 + kt + k2] = mo;
    }
  }

  // O: sum the two key-halves + transpose via LDS, 512-d chunks (chunk c = groups 2c,2c+1)
  #pragma unroll
  for (int c = 0; c < 2; ++c) {
    __syncthreads();
    if ((g >> 1) == c && s == 0) {
      #pragma unroll
      for (int hh = 0; hh < 4; ++hh)
        #pragma unroll
        for (int nd = 0; nd < 4; ++nd)
          #pragma unroll
          for (int j = 0; j < 4; ++j)
            Obuf[l15 * 513 + ((g & 1) * 4 + hh) * 64 + nd * 16 + lg * 4 + j] = oacc[hh][nd][j];
    }
    __syncthreads();
    if ((g >> 1) == c && s == 1) {
      #pragma unroll
      for (int hh = 0; hh < 4; ++hh)
        #pragma unroll
        for (int nd = 0; nd < 4; ++nd)
          #pragma unroll
          for (int j = 0; j < 4; ++j)
            Obuf[l15 * 513 + ((g & 1) * 4 + hh) * 64 + nd * 16 + lg * 4 + j] += oacc[hh][nd][j];
    }
    __syncthreads();
    #pragma unroll
    for (int r = 0; r < 4; ++r) {
      int flat = tid + r * 512;
      int q = flat >> 7, c4 = flat & 127;
      float4 v = *(const float4*)&Obuf[q * 513 + c4 * 4];
      *(float4*)&out[(size_t)(b * 512 + q0 + q) * 1024 + c * 512 + c4 * 4] = v;
    }
  }
}

extern "C" void kernel_launch(void* const* d_in, const int* in_sizes, int n_in,
                              void* d_out, int out_size, void* d_ws, size_t ws_size,
                              hipStream_t stream) {
  const float* text = (const float*)d_in[0];
  const float* av   = (const float*)d_in[1];
  const float* tn_w = (const float*)d_in[2];
  const float* tn_b = (const float*)d_in[3];
  const float* an_w = (const float*)d_in[4];
  const float* an_b = (const float*)d_in[5];
  const float* Wq   = (const float*)d_in[6];
  const float* bq   = (const float*)d_in[7];
  const float* Wk   = (const float*)d_in[8];
  const float* bk   = (const float*)d_in[9];
  const float* Wv   = (const float*)d_in[10];
  const float* bv   = (const float*)d_in[11];

  char* ws = (char*)d_ws;
  const size_t MB = 1u << 20;
  us* Wqb = (us*)(ws + 0 * MB);
  us* Wkb = (us*)(ws + 2 * MB);
  us* Wvb = (us*)(ws + 4 * MB);
  us* Tln = (us*)(ws + 6 * MB);
  us* Aln = (us*)(ws + 14 * MB);
  us* Qb  = (us*)(ws + 30 * MB);
  us* Kb  = (us*)(ws + 38 * MB);
  us* Vtb = (us*)(ws + 54 * MB);

  float* out  = (float*)d_out;
  float* mout = out + (size_t)8 * 512 * 1024;

  prep_kernel<<<15360, 256, 0, stream>>>(text, av, tn_w, tn_b, an_w, an_b,
                                         Wq, Wk, Wv, Tln, Aln, Wqb, Wkb, Wvb);
  gemm3_kernel<<<1280, 256, 0, stream>>>(Tln, Aln, Wqb, Wkb, Wvb,
                                         bq, bk, bv, Qb, Kb, Vtb);
  attn_kernel<<<256, 512, 0, stream>>>(Qb, Kb, Vtb, out, mout);
}